// Round 5
// baseline (268.686 us; speedup 1.0000x reference)
//
#include <hip/hip_runtime.h>
#include <hip/hip_bf16.h>
#include <hip/hip_fp16.h>

#define EPS 1e-8f
#define PI_F 3.14159265358979323846f

typedef _Float16 half8 __attribute__((ext_vector_type(8)));
typedef float f32x4 __attribute__((ext_vector_type(4)));
typedef float f32x2 __attribute__((ext_vector_type(2)));

__device__ __forceinline__ float gelu_exact(float v) {
    return 0.5f * v * (1.0f + erff(v * 0.70710678118654752f));
}

// ---------------------------------------------------------------------------
// Kernel 0: embed_w [256 k,512 col] fp32 -> permuted transposed fp16 hi/lo
// Wth/Wtl [512 j][256 k]. Also zero-inits XMsum/YMsum/pooled.
// ---------------------------------------------------------------------------
__global__ void convertW(const float* __restrict__ W,
                         _Float16* __restrict__ Wth, _Float16* __restrict__ Wtl,
                         float* __restrict__ zero_base) {
    int idx = blockIdx.x * 256 + threadIdx.x;   // 0..131071
    if (idx < 49152) zero_base[idx] = 0.f;      // XMsum,YMsum,pooled
    int col = idx & 511, k = idx >> 9;
    int d = col & 255, g = d >> 6;
    int j = g * 128 + ((col < 256) ? (d & 63) : (64 + (d & 63)));
    float f = W[k * 512 + col];
    _Float16 h = (_Float16)f;
    Wth[j * 256 + k] = h;
    Wtl[j * 256 + k] = (_Float16)(f - (float)h);
}

// ---------------------------------------------------------------------------
// Kernel 1: embed GEMM, NO LDS / NO BARRIERS. Fragments load directly from
// global (fragment = contiguous 16B per lane: row=l&15, k=(l>>4)*8..+8).
//  - B: fp16 hi/lo from Wth/Wtl (L2-hot; each group read by exactly 1 wave)
//  - A: fp32 from x, cvt to f16 hi/lo in registers
// 3 MFMA passes (Ah*Bh + Ah*Bl + Al*Bh) = fp32-grade h (R2 proved all three
// are needed: dropping Al*Bh gave absmax 0.203 > 0.166).
// Block tile 128m x 128n; wave w: m-half = w&1 (4 frags), n-groups
// {2a,2a+1,2a+4,2a+5}, a=w>>1 (so r/theta pairs are wave-local).
// XCD swizzle (R4-proven: FETCH 133->36 MB): id&7 -> XCD, g fastest within.
// ---------------------------------------------------------------------------
__global__ __launch_bounds__(256, 2) void gemm_embed(
    const float* __restrict__ x,
    const _Float16* __restrict__ Wth, const _Float16* __restrict__ Wtl,
    const float* __restrict__ bias,
    unsigned short* __restrict__ XY8,
    float* __restrict__ XMsum, float* __restrict__ YMsum)
{
    const int tid  = threadIdx.x;
    const int wave = tid >> 6;
    const int lane = tid & 63;
    const int id   = blockIdx.x;
    const int xcd  = id & 7;
    const int sidx = id >> 3;
    const int g    = sidx & 3;                 // d-range [64g, 64g+64)
    const int mt   = (sidx >> 2) * 8 + xcd;    // 0..511
    const int m0   = mt * 128;
    const int q    = lane >> 4, ln = lane & 15;
    const int mh   = wave & 1;                 // m-half (64 rows)
    const int a2   = wave >> 1;                // n pair-set

    // A offsets (float units): frag mi -> row m0 + mh*64 + mi*16 + ln
    int offA[4];
#pragma unroll
    for (int mi = 0; mi < 4; ++mi)
        offA[mi] = (m0 + mh * 64 + mi * 16 + ln) * 256 + q * 8;

    // B offsets (half units): groups {2a, 2a+1, 2a+4, 2a+5}
    int offB[4];
#pragma unroll
    for (int t = 0; t < 4; ++t) {
        int grp = 2 * a2 + (t & 1) + ((t >> 1) << 2);   // t:0,1,2,3 -> 2a,2a+1,2a+4,2a+5
        offB[t] = (g * 128 + grp * 16 + ln) * 256 + q * 8;
    }

    f32x4 acc[4][4];   // [mi][t]
#pragma unroll
    for (int mi = 0; mi < 4; ++mi)
#pragma unroll
        for (int t = 0; t < 4; ++t)
            acc[mi][t] = (f32x4){0.f, 0.f, 0.f, 0.f};

#pragma unroll 2
    for (int kt = 0; kt < 8; ++kt) {
        const int ka = kt * 32;
        half8 bh[4], bl[4], ah[4], al[4];
#pragma unroll
        for (int t = 0; t < 4; ++t) {
            bh[t] = *(const half8*)(Wth + (offB[t] + ka));
            bl[t] = *(const half8*)(Wtl + (offB[t] + ka));
        }
#pragma unroll
        for (int mi = 0; mi < 4; ++mi) {
            const float4 f0 = *(const float4*)(x + (offA[mi] + ka));
            const float4 f1 = *(const float4*)(x + (offA[mi] + ka + 4));
            half8 hh, ll;
            hh[0] = (_Float16)f0.x; ll[0] = (_Float16)(f0.x - (float)hh[0]);
            hh[1] = (_Float16)f0.y; ll[1] = (_Float16)(f0.y - (float)hh[1]);
            hh[2] = (_Float16)f0.z; ll[2] = (_Float16)(f0.z - (float)hh[2]);
            hh[3] = (_Float16)f0.w; ll[3] = (_Float16)(f0.w - (float)hh[3]);
            hh[4] = (_Float16)f1.x; ll[4] = (_Float16)(f1.x - (float)hh[4]);
            hh[5] = (_Float16)f1.y; ll[5] = (_Float16)(f1.y - (float)hh[5]);
            hh[6] = (_Float16)f1.z; ll[6] = (_Float16)(f1.z - (float)hh[6]);
            hh[7] = (_Float16)f1.w; ll[7] = (_Float16)(f1.w - (float)hh[7]);
            ah[mi] = hh; al[mi] = ll;
        }
        // 3 passes, 16 independent acc chains each
#pragma unroll
        for (int mi = 0; mi < 4; ++mi)
#pragma unroll
            for (int t = 0; t < 4; ++t)
                acc[mi][t] = __builtin_amdgcn_mfma_f32_16x16x32_f16(ah[mi], bh[t], acc[mi][t], 0, 0, 0);
#pragma unroll
        for (int mi = 0; mi < 4; ++mi)
#pragma unroll
            for (int t = 0; t < 4; ++t)
                acc[mi][t] = __builtin_amdgcn_mfma_f32_16x16x32_f16(ah[mi], bl[t], acc[mi][t], 0, 0, 0);
#pragma unroll
        for (int mi = 0; mi < 4; ++mi)
#pragma unroll
            for (int t = 0; t < 4; ++t)
                acc[mi][t] = __builtin_amdgcn_mfma_f32_16x16x32_f16(al[mi], bh[t], acc[mi][t], 0, 0, 0);
    }

    // ---- epilogue: pair t01 (r-part, group 2a+t01) with t01+2 (theta) ----
    // C/D layout: col = lane&15, row = (lane>>4)*4 + reg  [m89 verified]
    const int b = m0 >> 10;
#pragma unroll
    for (int t01 = 0; t01 < 2; ++t01) {
        const int d  = g * 64 + (2 * a2 + t01) * 16 + ln;
        const float b1 = bias[d];
        const float b2 = bias[256 + d];
        float sx = 0.f, sy = 0.f;
#pragma unroll
        for (int mi = 0; mi < 4; ++mi) {
#pragma unroll
            for (int i = 0; i < 4; ++i) {
                const int row = m0 + mh * 64 + mi * 16 + q * 4 + i;
                const float h1 = acc[mi][t01][i] + b1;
                const float h2 = acc[mi][t01 + 2][i] + b2;
                const float rr = fabsf(h1) + 0.1f;
                float sv, cv;
                __sincosf(PI_F * h2, &sv, &cv);
                const float xc = rr * cv, yc = rr * sv;
                int pk = __builtin_amdgcn_cvt_pk_fp8_f32(xc, yc, 0, false);
                XY8[(size_t)row * 256 + d] = (unsigned short)pk;
                sx += xc; sy += yc;    // mean path stays full fp32
            }
        }
        // lanes l, l+16, l+32, l+48 share d (different row-quads)
        sx += __shfl_down(sx, 32); sx += __shfl_down(sx, 16);
        sy += __shfl_down(sy, 32); sy += __shfl_down(sy, 16);
        if (lane < 16) {
            atomicAdd(&XMsum[b * 256 + d], sx);
            atomicAdd(&YMsum[b * 256 + d], sy);
        }
    }
}

// ---------------------------------------------------------------------------
// Kernel 2: 8-layer recurrence on the means. 8 threads per (b,d), 4 k-units
// each, shfl_xor(1,2,4) reduction.
// ---------------------------------------------------------------------------
__global__ __launch_bounds__(256) void layers_kernel(
    const float* __restrict__ XMsum, const float* __restrict__ YMsum,
    const float* __restrict__ mw1, const float* __restrict__ mb1,
    const float* __restrict__ mw2, const float* __restrict__ mb2,
    const float* __restrict__ pw1, const float* __restrict__ pb1,
    const float* __restrict__ pw2, const float* __restrict__ pb2,
    float* __restrict__ DX, float* __restrict__ DY)
{
    __shared__ float s_mw1[256], s_mb1[256], s_mw2[256], s_mb2[8];
    __shared__ float s_pw1[512], s_pb1[256], s_pw2[512], s_pb2[16];
    const int tid = threadIdx.x;
    s_mw1[tid] = mw1[tid]; s_mb1[tid] = mb1[tid];
    s_mw2[tid] = mw2[tid]; s_pb1[tid] = pb1[tid];
    s_pw1[tid] = pw1[tid]; s_pw1[256 + tid] = pw1[256 + tid];
    s_pw2[tid] = pw2[tid]; s_pw2[256 + tid] = pw2[256 + tid];
    if (tid < 8)  s_mb2[tid] = mb2[tid];
    if (tid < 16) s_pb2[tid] = pb2[tid];
    __syncthreads();

    const int gid = blockIdx.x * 256 + tid;
    const int idx = gid >> 3;                 // (b,d), 16384
    const int sub = gid & 7;                  // k-eighth
    float xm = XMsum[idx] * (1.0f / 1024.0f);
    float ym = YMsum[idx] * (1.0f / 1024.0f);
    float dxa = 0.f, dya = 0.f;
#pragma unroll 1
    for (int i = 0; i < 8; ++i) {
        float r2    = xm * xm + ym * ym;
        float r_agg = sqrtf(r2 + EPS);
        float hyp   = sqrtf(r2);
        float inv   = hyp > 0.f ? 1.0f / hyp : 0.f;
        float st    = ym * inv;
        float ct    = hyp > 0.f ? xm * inv : 1.0f;
        float log_r = logf(r_agg + EPS);
        float lr = 0.f, p0 = 0.f, p1 = 0.f;
#pragma unroll
        for (int k4 = 0; k4 < 4; ++k4) {
            int k = sub * 4 + k4;
            float hm = gelu_exact(log_r * s_mw1[i * 32 + k] + s_mb1[i * 32 + k]);
            lr += hm * s_mw2[i * 32 + k];
            float hp = gelu_exact(st * s_pw1[i * 64 + k] + ct * s_pw1[i * 64 + 32 + k] + s_pb1[i * 32 + k]);
            p0 += hp * s_pw2[i * 64 + 2 * k + 0];
            p1 += hp * s_pw2[i * 64 + 2 * k + 1];
        }
        lr += __shfl_xor(lr, 1); lr += __shfl_xor(lr, 2); lr += __shfl_xor(lr, 4);
        p0 += __shfl_xor(p0, 1); p0 += __shfl_xor(p0, 2); p0 += __shfl_xor(p0, 4);
        p1 += __shfl_xor(p1, 1); p1 += __shfl_xor(p1, 2); p1 += __shfl_xor(p1, 4);
        lr += s_mb2[i];
        p0 += s_pb2[i * 2 + 0];
        p1 += s_pb2[i * 2 + 1];
        float r_trans = expf(lr);
        float hp2  = sqrtf(p0 * p0 + p1 * p1);
        float invp = hp2 > 0.f ? 1.0f / hp2 : 0.f;
        float ctt  = hp2 > 0.f ? p1 * invp : 1.0f;
        float stt  = p0 * invp;
        float dx = r_trans * ctt;
        float dy = r_trans * stt;
        dxa += dx; dya += dy; xm += dx; ym += dy;
    }
    if (sub == 0) { DX[idx] = dxa; DY[idx] = dya; }
}

// ---------------------------------------------------------------------------
// Kernel 3: pooled[b,d] += sum_s sqrt((xc+DX)^2 + (yc+DY)^2 + EPS)
// XY8 packed fp8 pairs; 16B loads = 8 d's per thread. LDS reduce over the
// 8 s-subgroups (pad 9 -> conflict-free), 1 atomic per d.
// ---------------------------------------------------------------------------
__global__ __launch_bounds__(256) void pool_kernel(
    const unsigned short* __restrict__ XY8,
    const float* __restrict__ DX, const float* __restrict__ DY,
    float* __restrict__ pooled)
{
    __shared__ float red[256][9];
    const int b = blockIdx.x, sc = blockIdx.y, tid = threadIdx.x;
    const int dg = tid & 31;           // d-group: d = dg*8 .. dg*8+7
    const int sh = tid >> 5;           // s-subchunk (16 rows each)
    const int d0 = dg * 8;
    float dxv[8], dyv[8], s[8];
#pragma unroll
    for (int j = 0; j < 8; ++j) {
        dxv[j] = DX[b * 256 + d0 + j];
        dyv[j] = DY[b * 256 + d0 + j];
        s[j] = 0.f;
    }
    const int r0 = sc * 128 + sh * 16;
    const size_t base = ((size_t)b * 1024 + r0) * 256 + d0;
#pragma unroll 4
    for (int i = 0; i < 16; ++i) {
        const int4 v = *(const int4*)(XY8 + base + (size_t)i * 256);
        const int wv[4] = {v.x, v.y, v.z, v.w};
#pragma unroll
        for (int w = 0; w < 4; ++w) {
            f32x2 pa = __builtin_amdgcn_cvt_pk_f32_fp8(wv[w], false);
            f32x2 pb = __builtin_amdgcn_cvt_pk_f32_fp8(wv[w], true);
            float xa = pa[0] + dxv[2 * w],     ya = pa[1] + dyv[2 * w];
            float xb = pb[0] + dxv[2 * w + 1], yb = pb[1] + dyv[2 * w + 1];
            s[2 * w]     += sqrtf(xa * xa + ya * ya + EPS);
            s[2 * w + 1] += sqrtf(xb * xb + yb * yb + EPS);
        }
    }
#pragma unroll
    for (int j = 0; j < 8; ++j) red[tid][j] = s[j];
    __syncthreads();
    if (tid < 32) {
#pragma unroll
        for (int j = 0; j < 8; ++j) {
            float t = 0.f;
#pragma unroll
            for (int c = 0; c < 8; ++c) t += red[c * 32 + tid][j];
            atomicAdd(&pooled[b * 256 + tid * 8 + j], t);
        }
    }
}

// ---------------------------------------------------------------------------
// Kernel 4: classifier  gelu(pooled/1024 @ w1 + b1) @ w2 + b2  -> [64,1000]
// ---------------------------------------------------------------------------
__global__ __launch_bounds__(256) void cls_kernel(
    const float* __restrict__ pooled,
    const float* __restrict__ w1, const float* __restrict__ b1,
    const float* __restrict__ w2, const float* __restrict__ b2,
    float* __restrict__ out)
{
    __shared__ float pl[256];
    __shared__ float part[8][32];
    __shared__ float hd[32];
    const int b = blockIdx.x, tid = threadIdx.x;
    pl[tid] = pooled[b * 256 + tid] * (1.0f / 1024.0f);
    __syncthreads();
    const int hu = tid & 31, kc = tid >> 5;
    float a = 0.f;
    for (int k = kc * 32; k < kc * 32 + 32; ++k) a += pl[k] * w1[k * 32 + hu];
    part[kc][hu] = a;
    __syncthreads();
    if (tid < 32) {
        float s = b1[tid];
#pragma unroll
        for (int c = 0; c < 8; ++c) s += part[c][tid];
        hd[tid] = gelu_exact(s);
    }
    __syncthreads();
    for (int n = tid; n < 1000; n += 256) {
        float s = b2[n];
#pragma unroll
        for (int k = 0; k < 32; ++k) s += hd[k] * w2[k * 1000 + n];
        out[b * 1000 + n] = s;
    }
}

// ---------------------------------------------------------------------------
extern "C" void kernel_launch(void* const* d_in, const int* in_sizes, int n_in,
                              void* d_out, int out_size, void* d_ws, size_t ws_size,
                              hipStream_t stream)
{
    const float* x       = (const float*)d_in[0];
    const float* embed_w = (const float*)d_in[1];
    const float* embed_b = (const float*)d_in[2];
    const float* mag_w1  = (const float*)d_in[3];
    const float* mag_b1  = (const float*)d_in[4];
    const float* mag_w2  = (const float*)d_in[5];
    const float* mag_b2  = (const float*)d_in[6];
    const float* ph_w1   = (const float*)d_in[7];
    const float* ph_b1   = (const float*)d_in[8];
    const float* ph_w2   = (const float*)d_in[9];
    const float* ph_b2   = (const float*)d_in[10];
    const float* cls_w1  = (const float*)d_in[11];
    const float* cls_b1  = (const float*)d_in[12];
    const float* cls_w2  = (const float*)d_in[13];
    const float* cls_b2  = (const float*)d_in[14];
    float* out = (float*)d_out;

    char* ws = (char*)d_ws;
    unsigned short* XY8 = (unsigned short*)(ws + 0);   // 33554432 B (fp8 pairs)
    _Float16* Wth = (_Float16*)(ws + 33554432);        // 262144
    _Float16* Wtl = (_Float16*)(ws + 33816576);        // 262144
    float* XMsum  = (float*)(ws + 34078720);           // 65536
    float* YMsum  = (float*)(ws + 34144256);           // 65536
    float* pooled = (float*)(ws + 34209792);           // 65536
    float* DX     = (float*)(ws + 34275328);           // 65536
    float* DY     = (float*)(ws + 34340864);           // 65536

    convertW<<<512, 256, 0, stream>>>(embed_w, Wth, Wtl, XMsum);  // zeros XMsum,YMsum,pooled
    gemm_embed<<<2048, 256, 0, stream>>>(x, Wth, Wtl, embed_b, XY8, XMsum, YMsum);
    layers_kernel<<<512, 256, 0, stream>>>(XMsum, YMsum, mag_w1, mag_b1, mag_w2, mag_b2,
                                           ph_w1, ph_b1, ph_w2, ph_b2, DX, DY);
    pool_kernel<<<dim3(64, 8), 256, 0, stream>>>(XY8, DX, DY, pooled);
    cls_kernel<<<64, 256, 0, stream>>>(pooled, cls_w1, cls_b1, cls_w2, cls_b2, out);
}

// Round 6
// 220.870 us; speedup vs baseline: 1.2165x; 1.2165x over previous
//
#include <hip/hip_runtime.h>
#include <hip/hip_bf16.h>
#include <hip/hip_fp16.h>

#define EPS 1e-8f
#define PI_F 3.14159265358979323846f

typedef _Float16 half8 __attribute__((ext_vector_type(8)));
typedef float f32x4 __attribute__((ext_vector_type(4)));
typedef float f32x2 __attribute__((ext_vector_type(2)));

__device__ __forceinline__ float gelu_exact(float v) {
    return 0.5f * v * (1.0f + erff(v * 0.70710678118654752f));
}

// ---------------------------------------------------------------------------
// Kernel 0: embed_w [256 k,512 col] fp32 -> B in MFMA-FRAGMENT layout, fp16
// hi/lo.  Chunk (g,grp,kt32) = 512 halves: half index =
// ((g*8+grp)*8 + kt32)*512 + lane*8 + e, holding W^T[j = g*128+grp*16+ln]
// [k = kt32*32 + q*8 + e]  (lane = q*16+ln).  Output-indexed => writes
// perfectly coalesced; scattered reads are L2-hot (W = 512 KB).
// Also zero-inits XMsum/YMsum/pooled (contiguous 48K floats).
// ---------------------------------------------------------------------------
__global__ void convertW(const float* __restrict__ W,
                         _Float16* __restrict__ Bfh, _Float16* __restrict__ Bfl,
                         float* __restrict__ zero_base) {
    int idx = blockIdx.x * 256 + threadIdx.x;   // 0..131071 (output half index)
    if (idx < 49152) zero_base[idx] = 0.f;      // XMsum,YMsum,pooled
    int e     = idx & 7;
    int lane  = (idx >> 3) & 63;
    int chunk = idx >> 9;                       // 0..255
    int kt32  = chunk & 7;
    int gg    = chunk >> 3;                     // 0..31
    int g     = gg >> 3, grp = gg & 7;
    int q     = lane >> 4, ln = lane & 15;
    int j     = g * 128 + grp * 16 + ln;        // permuted row 0..511
    int k     = kt32 * 32 + q * 8 + e;          // 0..255
    int jj    = j & 127;
    int d     = g * 64 + (jj & 63);
    int col   = (jj < 64) ? d : (256 + d);
    float f = W[k * 512 + col];
    _Float16 h = (_Float16)f;
    Bfh[idx] = h;
    Bfl[idx] = (_Float16)(f - (float)h);
}

// ---------------------------------------------------------------------------
// Kernel 1: embed GEMM. A staged in LDS (fp32 -> fp16 hi/lo, BK=64, XOR
// swizzle pos = c ^ (row&7) => 2-way bank alias, free). B-fragments loaded
// DIRECTLY global->VGPR from the pre-formatted Bfh/Bfl (lane-contiguous 1KB
// chunks, perfectly coalesced, L2-hot) -- no B staging, no B LDS traffic.
// (R5 lesson: direct fragment loads are only viable lane-contiguous.)
// 3 MFMA passes (Ah*Bh + Ah*Bl + Al*Bh) = fp32-grade h (R2: all 3 needed).
// Tile 128m x 128n; wave (mh = w&1, a2 = w>>1): m-half 64 rows, n-groups
// {2a2, 2a2+1, 2a2+4, 2a2+5} (r/theta pairs wave-local; R5-verified).
// XCD swizzle (R4-proven: FETCH 133->36 MB): id&7 -> XCD, g fastest within.
// ---------------------------------------------------------------------------
__global__ __launch_bounds__(256, 3) void gemm_embed(
    const float* __restrict__ x,
    const _Float16* __restrict__ Bfh, const _Float16* __restrict__ Bfl,
    const float* __restrict__ bias,
    unsigned short* __restrict__ XY8,
    float* __restrict__ XMsum, float* __restrict__ YMsum)
{
    __shared__ __attribute__((aligned(16))) _Float16 Ah[8192], Al[8192]; // 32 KB
    const int tid  = threadIdx.x;
    const int wave = tid >> 6;
    const int lane = tid & 63;
    const int id   = blockIdx.x;
    const int xcd  = id & 7;
    const int sidx = id >> 3;
    const int g    = sidx & 3;                 // d-range [64g, 64g+64)
    const int mt   = (sidx >> 2) * 8 + xcd;    // 0..511
    const int m0   = mt * 128;
    const int q    = lane >> 4, ln = lane & 15;
    const int mh   = wave & 1;                 // m-half (64 rows)
    const int a2   = wave >> 1;                // n pair-set

    // B fragment chunk bases (half units); add (kt*2+ks)*512 in the loop
    int offB[4];
#pragma unroll
    for (int t = 0; t < 4; ++t) {
        int grp = 2 * a2 + (t & 1) + ((t >> 1) << 2);  // 2a2,2a2+1,2a2+4,2a2+5
        offB[t] = ((g * 8 + grp) * 8) * 512 + lane * 8;
    }
    // A staging coords: thread -> row r = tid>>1, k-half h = tid&1
    const int sr = tid >> 1, shh = tid & 1;
    const float* srcA = x + (size_t)(m0 + sr) * 256 + shh * 32;

    f32x4 acc[4][4];   // [mi][t]
#pragma unroll
    for (int mi = 0; mi < 4; ++mi)
#pragma unroll
        for (int t = 0; t < 4; ++t)
            acc[mi][t] = (f32x4){0.f, 0.f, 0.f, 0.f};

    for (int kt = 0; kt < 4; ++kt) {
        __syncthreads();
        // ---- stage A [128 rows][64 k] fp32 -> fp16 hi/lo, swizzled ----
        {
            const float* src = srcA + kt * 64;
            float4 f[8];
#pragma unroll
            for (int i = 0; i < 8; ++i) f[i] = *(const float4*)(src + i * 4);
#pragma unroll
            for (int cc = 0; cc < 4; ++cc) {
                const float fv[8] = { f[2*cc].x, f[2*cc].y, f[2*cc].z, f[2*cc].w,
                                      f[2*cc+1].x, f[2*cc+1].y, f[2*cc+1].z, f[2*cc+1].w };
                half8 hv, lv;
#pragma unroll
                for (int e = 0; e < 8; ++e) {
                    hv[e] = (_Float16)fv[e];
                    lv[e] = (_Float16)(fv[e] - (float)hv[e]);
                }
                int c   = shh * 4 + cc;
                int pos = c ^ (sr & 7);
                *(half8*)&Ah[sr * 64 + pos * 8] = hv;
                *(half8*)&Al[sr * 64 + pos * 8] = lv;
            }
        }
        __syncthreads();

#pragma unroll
        for (int ks = 0; ks < 2; ++ks) {
            // ---- B fragments: direct coalesced global loads (L2-hot) ----
            const int kc = (kt * 2 + ks) * 512;
            half8 bh[4], bl[4];
#pragma unroll
            for (int t = 0; t < 4; ++t) {
                bh[t] = *(const half8*)(Bfh + offB[t] + kc);
                bl[t] = *(const half8*)(Bfl + offB[t] + kc);
            }
            // ---- A fragments from LDS ----
            half8 ah[4], al[4];
#pragma unroll
            for (int mi = 0; mi < 4; ++mi) {
                int row = mh * 64 + mi * 16 + ln;
                int pos = (ks * 4 + q) ^ (row & 7);
                int off = row * 64 + pos * 8;
                ah[mi] = *(const half8*)&Ah[off];
                al[mi] = *(const half8*)&Al[off];
            }
            // ---- 3 passes x 16 independent MFMAs ----
#pragma unroll
            for (int mi = 0; mi < 4; ++mi)
#pragma unroll
                for (int t = 0; t < 4; ++t)
                    acc[mi][t] = __builtin_amdgcn_mfma_f32_16x16x32_f16(ah[mi], bh[t], acc[mi][t], 0, 0, 0);
#pragma unroll
            for (int mi = 0; mi < 4; ++mi)
#pragma unroll
                for (int t = 0; t < 4; ++t)
                    acc[mi][t] = __builtin_amdgcn_mfma_f32_16x16x32_f16(ah[mi], bl[t], acc[mi][t], 0, 0, 0);
#pragma unroll
            for (int mi = 0; mi < 4; ++mi)
#pragma unroll
                for (int t = 0; t < 4; ++t)
                    acc[mi][t] = __builtin_amdgcn_mfma_f32_16x16x32_f16(al[mi], bh[t], acc[mi][t], 0, 0, 0);
        }
    }

    // ---- epilogue (R5-verified): pair t01 (r, grp 2a2+t01) with t01+2 ----
    // C/D layout: col = lane&15, row = (lane>>4)*4 + reg  [m89 verified]
    const int b = m0 >> 10;
#pragma unroll
    for (int t01 = 0; t01 < 2; ++t01) {
        const int d  = g * 64 + (2 * a2 + t01) * 16 + ln;
        const float b1 = bias[d];
        const float b2 = bias[256 + d];
        float sx = 0.f, sy = 0.f;
#pragma unroll
        for (int mi = 0; mi < 4; ++mi) {
#pragma unroll
            for (int i = 0; i < 4; ++i) {
                const int row = m0 + mh * 64 + mi * 16 + q * 4 + i;
                const float h1 = acc[mi][t01][i] + b1;
                const float h2 = acc[mi][t01 + 2][i] + b2;
                const float rr = fabsf(h1) + 0.1f;
                float sv, cv;
                __sincosf(PI_F * h2, &sv, &cv);
                const float xc = rr * cv, yc = rr * sv;
                int pk = __builtin_amdgcn_cvt_pk_fp8_f32(xc, yc, 0, false);
                XY8[(size_t)row * 256 + d] = (unsigned short)pk;
                sx += xc; sy += yc;    // mean path stays full fp32
            }
        }
        sx += __shfl_down(sx, 32); sx += __shfl_down(sx, 16);
        sy += __shfl_down(sy, 32); sy += __shfl_down(sy, 16);
        if (lane < 16) {
            atomicAdd(&XMsum[b * 256 + d], sx);
            atomicAdd(&YMsum[b * 256 + d], sy);
        }
    }
}

// ---------------------------------------------------------------------------
// Kernel 2: 8-layer recurrence on the means. 8 threads per (b,d), 4 k-units
// each, shfl_xor(1,2,4) reduction.
// ---------------------------------------------------------------------------
__global__ __launch_bounds__(256) void layers_kernel(
    const float* __restrict__ XMsum, const float* __restrict__ YMsum,
    const float* __restrict__ mw1, const float* __restrict__ mb1,
    const float* __restrict__ mw2, const float* __restrict__ mb2,
    const float* __restrict__ pw1, const float* __restrict__ pb1,
    const float* __restrict__ pw2, const float* __restrict__ pb2,
    float* __restrict__ DX, float* __restrict__ DY)
{
    __shared__ float s_mw1[256], s_mb1[256], s_mw2[256], s_mb2[8];
    __shared__ float s_pw1[512], s_pb1[256], s_pw2[512], s_pb2[16];
    const int tid = threadIdx.x;
    s_mw1[tid] = mw1[tid]; s_mb1[tid] = mb1[tid];
    s_mw2[tid] = mw2[tid]; s_pb1[tid] = pb1[tid];
    s_pw1[tid] = pw1[tid]; s_pw1[256 + tid] = pw1[256 + tid];
    s_pw2[tid] = pw2[tid]; s_pw2[256 + tid] = pw2[256 + tid];
    if (tid < 8)  s_mb2[tid] = mb2[tid];
    if (tid < 16) s_pb2[tid] = pb2[tid];
    __syncthreads();

    const int gid = blockIdx.x * 256 + tid;
    const int idx = gid >> 3;                 // (b,d), 16384
    const int sub = gid & 7;                  // k-eighth
    float xm = XMsum[idx] * (1.0f / 1024.0f);
    float ym = YMsum[idx] * (1.0f / 1024.0f);
    float dxa = 0.f, dya = 0.f;
#pragma unroll 1
    for (int i = 0; i < 8; ++i) {
        float r2    = xm * xm + ym * ym;
        float r_agg = sqrtf(r2 + EPS);
        float hyp   = sqrtf(r2);
        float inv   = hyp > 0.f ? 1.0f / hyp : 0.f;
        float st    = ym * inv;
        float ct    = hyp > 0.f ? xm * inv : 1.0f;
        float log_r = logf(r_agg + EPS);
        float lr = 0.f, p0 = 0.f, p1 = 0.f;
#pragma unroll
        for (int k4 = 0; k4 < 4; ++k4) {
            int k = sub * 4 + k4;
            float hm = gelu_exact(log_r * s_mw1[i * 32 + k] + s_mb1[i * 32 + k]);
            lr += hm * s_mw2[i * 32 + k];
            float hp = gelu_exact(st * s_pw1[i * 64 + k] + ct * s_pw1[i * 64 + 32 + k] + s_pb1[i * 32 + k]);
            p0 += hp * s_pw2[i * 64 + 2 * k + 0];
            p1 += hp * s_pw2[i * 64 + 2 * k + 1];
        }
        lr += __shfl_xor(lr, 1); lr += __shfl_xor(lr, 2); lr += __shfl_xor(lr, 4);
        p0 += __shfl_xor(p0, 1); p0 += __shfl_xor(p0, 2); p0 += __shfl_xor(p0, 4);
        p1 += __shfl_xor(p1, 1); p1 += __shfl_xor(p1, 2); p1 += __shfl_xor(p1, 4);
        lr += s_mb2[i];
        p0 += s_pb2[i * 2 + 0];
        p1 += s_pb2[i * 2 + 1];
        float r_trans = expf(lr);
        float hp2  = sqrtf(p0 * p0 + p1 * p1);
        float invp = hp2 > 0.f ? 1.0f / hp2 : 0.f;
        float ctt  = hp2 > 0.f ? p1 * invp : 1.0f;
        float stt  = p0 * invp;
        float dx = r_trans * ctt;
        float dy = r_trans * stt;
        dxa += dx; dya += dy; xm += dx; ym += dy;
    }
    if (sub == 0) { DX[idx] = dxa; DY[idx] = dya; }
}

// ---------------------------------------------------------------------------
// Kernel 3: pooled[b,d] += sum_s sqrt((xc+DX)^2 + (yc+DY)^2 + EPS)
// XY8 packed fp8 pairs; 16B loads = 8 d's per thread. LDS reduce over the
// 8 s-subgroups (pad 9 -> conflict-free), 1 atomic per d.
// ---------------------------------------------------------------------------
__global__ __launch_bounds__(256) void pool_kernel(
    const unsigned short* __restrict__ XY8,
    const float* __restrict__ DX, const float* __restrict__ DY,
    float* __restrict__ pooled)
{
    __shared__ float red[256][9];
    const int b = blockIdx.x, sc = blockIdx.y, tid = threadIdx.x;
    const int dg = tid & 31;           // d-group: d = dg*8 .. dg*8+7
    const int sh = tid >> 5;           // s-subchunk (16 rows each)
    const int d0 = dg * 8;
    float dxv[8], dyv[8], s[8];
#pragma unroll
    for (int j = 0; j < 8; ++j) {
        dxv[j] = DX[b * 256 + d0 + j];
        dyv[j] = DY[b * 256 + d0 + j];
        s[j] = 0.f;
    }
    const int r0 = sc * 128 + sh * 16;
    const size_t base = ((size_t)b * 1024 + r0) * 256 + d0;
#pragma unroll 4
    for (int i = 0; i < 16; ++i) {
        const int4 v = *(const int4*)(XY8 + base + (size_t)i * 256);
        const int wv[4] = {v.x, v.y, v.z, v.w};
#pragma unroll
        for (int w = 0; w < 4; ++w) {
            f32x2 pa = __builtin_amdgcn_cvt_pk_f32_fp8(wv[w], false);
            f32x2 pb = __builtin_amdgcn_cvt_pk_f32_fp8(wv[w], true);
            float xa = pa[0] + dxv[2 * w],     ya = pa[1] + dyv[2 * w];
            float xb = pb[0] + dxv[2 * w + 1], yb = pb[1] + dyv[2 * w + 1];
            s[2 * w]     += sqrtf(xa * xa + ya * ya + EPS);
            s[2 * w + 1] += sqrtf(xb * xb + yb * yb + EPS);
        }
    }
#pragma unroll
    for (int j = 0; j < 8; ++j) red[tid][j] = s[j];
    __syncthreads();
    if (tid < 32) {
#pragma unroll
        for (int j = 0; j < 8; ++j) {
            float t = 0.f;
#pragma unroll
            for (int c = 0; c < 8; ++c) t += red[c * 32 + tid][j];
            atomicAdd(&pooled[b * 256 + tid * 8 + j], t);
        }
    }
}

// ---------------------------------------------------------------------------
// Kernel 4: classifier  gelu(pooled/1024 @ w1 + b1) @ w2 + b2  -> [64,1000]
// ---------------------------------------------------------------------------
__global__ __launch_bounds__(256) void cls_kernel(
    const float* __restrict__ pooled,
    const float* __restrict__ w1, const float* __restrict__ b1,
    const float* __restrict__ w2, const float* __restrict__ b2,
    float* __restrict__ out)
{
    __shared__ float pl[256];
    __shared__ float part[8][32];
    __shared__ float hd[32];
    const int b = blockIdx.x, tid = threadIdx.x;
    pl[tid] = pooled[b * 256 + tid] * (1.0f / 1024.0f);
    __syncthreads();
    const int hu = tid & 31, kc = tid >> 5;
    float a = 0.f;
    for (int k = kc * 32; k < kc * 32 + 32; ++k) a += pl[k] * w1[k * 32 + hu];
    part[kc][hu] = a;
    __syncthreads();
    if (tid < 32) {
        float s = b1[tid];
#pragma unroll
        for (int c = 0; c < 8; ++c) s += part[c][tid];
        hd[tid] = gelu_exact(s);
    }
    __syncthreads();
    for (int n = tid; n < 1000; n += 256) {
        float s = b2[n];
#pragma unroll
        for (int k = 0; k < 32; ++k) s += hd[k] * w2[k * 1000 + n];
        out[b * 1000 + n] = s;
    }
}

// ---------------------------------------------------------------------------
extern "C" void kernel_launch(void* const* d_in, const int* in_sizes, int n_in,
                              void* d_out, int out_size, void* d_ws, size_t ws_size,
                              hipStream_t stream)
{
    const float* x       = (const float*)d_in[0];
    const float* embed_w = (const float*)d_in[1];
    const float* embed_b = (const float*)d_in[2];
    const float* mag_w1  = (const float*)d_in[3];
    const float* mag_b1  = (const float*)d_in[4];
    const float* mag_w2  = (const float*)d_in[5];
    const float* mag_b2  = (const float*)d_in[6];
    const float* ph_w1   = (const float*)d_in[7];
    const float* ph_b1   = (const float*)d_in[8];
    const float* ph_w2   = (const float*)d_in[9];
    const float* ph_b2   = (const float*)d_in[10];
    const float* cls_w1  = (const float*)d_in[11];
    const float* cls_b1  = (const float*)d_in[12];
    const float* cls_w2  = (const float*)d_in[13];
    const float* cls_b2  = (const float*)d_in[14];
    float* out = (float*)d_out;

    char* ws = (char*)d_ws;
    unsigned short* XY8 = (unsigned short*)(ws + 0);   // 33554432 B (fp8 pairs)
    _Float16* Bfh = (_Float16*)(ws + 33554432);        // 262144 (frag layout)
    _Float16* Bfl = (_Float16*)(ws + 33816576);        // 262144
    float* XMsum  = (float*)(ws + 34078720);           // 65536
    float* YMsum  = (float*)(ws + 34144256);           // 65536
    float* pooled = (float*)(ws + 34209792);           // 65536
    float* DX     = (float*)(ws + 34275328);           // 65536
    float* DY     = (float*)(ws + 34340864);           // 65536

    convertW<<<512, 256, 0, stream>>>(embed_w, Bfh, Bfl, XMsum);  // zeros XMsum,YMsum,pooled
    gemm_embed<<<2048, 256, 0, stream>>>(x, Bfh, Bfl, embed_b, XY8, XMsum, YMsum);
    layers_kernel<<<512, 256, 0, stream>>>(XMsum, YMsum, mag_w1, mag_b1, mag_w2, mag_b2,
                                           ph_w1, ph_b1, ph_w2, ph_b2, DX, DY);
    pool_kernel<<<dim3(64, 8), 256, 0, stream>>>(XY8, DX, DY, pooled);
    cls_kernel<<<64, 256, 0, stream>>>(pooled, cls_w1, cls_b1, cls_w2, cls_b2, out);
}